// Round 7
// baseline (1128.534 us; speedup 1.0000x reference)
//
#include <hip/hip_runtime.h>

#define BB 256
#define SS 200
#define MM 32
#define KDIM 128
#define VDIM 256
#define QDIM 128
#define HH 64
#define NROWS 10001
#define NSAMP (BB*SS)
#define INDIM (VDIM+QDIM)
#define HSIZE 32768
#define HMASK (HSIZE-1)
#define HEMPTY 0xFFFFFFFFFFFFFFFFULL

typedef unsigned long long u64;
typedef unsigned int u32;

__device__ __forceinline__ float sigm(float x){ return 1.0f/(1.0f+expf(-x)); }
__device__ __forceinline__ int clampq(int q){ return q < 0 ? 0 : (q > NROWS-1 ? NROWS-1 : q); }

__device__ __forceinline__ u32 hash64(u64 x){
  x ^= x >> 33; x *= 0xff51afd7ed558ccdULL;
  x ^= x >> 33; x *= 0xc4ceb9fe1a85ec53ULL;
  x ^= x >> 33;
  return (u32)x;
}

// VW[m][j] = sum_v value_mem[m,v] * W_ih[j,v]   (read-part of W_ih)
__global__ void k_vw(const float* __restrict__ val, const float* __restrict__ W_ih,
                     float* __restrict__ VW){
  int t = blockIdx.x*blockDim.x + threadIdx.x;
  if (t >= MM*256) return;
  int m = t >> 8, j = t & 255;
  float acc = 0.f;
  for (int v = 0; v < VDIM; ++v)
    acc += val[m*VDIM+v] * W_ih[j*INDIM+v];
  VW[m*256+j] = acc;
}

__global__ void k_init(u64* __restrict__ htab, u32* __restrict__ counter){
  int t = blockIdx.x*blockDim.x + threadIdx.x;
  if (t < HSIZE) htab[t] = HEMPTY;
  if (t == 0) *counter = 0u;
}

// Per embedding row n: cw = softmax(emb_n . K^T); trit key (reference packing:
// kh = sum iv[0:16]*3^m LSB-first, kl = sum iv[16:32]*3^m; rank order = (kh,kl)
// ascending = combined kh*3^16+kl); XW[n,j] = cw.VW[:,j] + emb_n.Wq[j,:] + b_ih[j]+b_hh[j]
__global__ __launch_bounds__(256) void k_table(
    const float* __restrict__ emb, const float* __restrict__ key_mem,
    const float* __restrict__ W_ih, const float* __restrict__ b_ih,
    const float* __restrict__ b_hh, const float* __restrict__ VW,
    float* __restrict__ XW, u64* __restrict__ KEYT){
  int n = blockIdx.x, tid = threadIdx.x;
  __shared__ float se[QDIM];
  __shared__ float slog[MM];
  __shared__ float scw[MM];
  __shared__ float svw[MM*256];
  if (tid < QDIM) se[tid] = emb[n*QDIM + tid];
  for (int t = tid; t < MM*256; t += 256) svw[t] = VW[t];
  __syncthreads();
  if (tid < MM) {
    float acc = 0.f;
    for (int d = 0; d < KDIM; ++d) acc += se[d]*key_mem[tid*KDIM+d];
    slog[tid] = acc;
  }
  __syncthreads();
  if (tid == 0) {
    float mx = slog[0];
    #pragma unroll
    for (int m = 1; m < MM; ++m) mx = fmaxf(mx, slog[m]);
    float sum = 0.f;
    #pragma unroll
    for (int m = 0; m < MM; ++m) { float e = expf(slog[m]-mx); scw[m] = e; sum += e; }
    int iv[MM];
    #pragma unroll
    for (int m = 0; m < MM; ++m) {
      float cw = scw[m]/sum; scw[m] = cw;
      // f32 semantics: divisors are f32(0.088-0.075)=0.013f, f32(1.0-0.088)=0.912f
      float w = fminf((cw - 0.075f)/0.013f, (1.0f - cw)/0.912f);
      w = fmaxf(w, 0.0f);
      iv[m] = (w >= 0.6f) ? 2 : ((w >= 0.1f) ? 1 : 0);
    }
    u64 kh = 0, kl = 0, p = 1;
    #pragma unroll
    for (int m = 0; m < 16; ++m) { kh += (u64)iv[m]*p; p *= 3ULL; }
    p = 1;
    #pragma unroll
    for (int m = 16; m < 32; ++m) { kl += (u64)iv[m]*p; p *= 3ULL; }
    KEYT[n] = kh*43046721ULL + kl;   // 3^16: ascending == lexsort((kl,kh))
  }
  __syncthreads();
  float acc = b_ih[tid] + b_hh[tid];
  #pragma unroll
  for (int m = 0; m < MM; ++m) acc += scw[m]*svw[m*256+tid];
  const float* wrow = W_ih + tid*INDIM + VDIM;
  for (int d = 0; d < QDIM; ++d) acc += se[d]*wrow[d];
  XW[n*256 + tid] = acc;
}

__global__ void k_insert(const int* __restrict__ q_data, const u64* __restrict__ KEYT,
                         u64* __restrict__ htab, u32* __restrict__ payload,
                         u32* __restrict__ counter, u64* __restrict__ uniq){
  int i = blockIdx.x*blockDim.x + threadIdx.x;
  if (i >= NSAMP) return;
  u64 key = KEYT[clampq(q_data[i])];
  u32 h = hash64(key) & HMASK;
  while (true) {
    u64 prev = atomicCAS(&htab[h], HEMPTY, key);
    if (prev == HEMPTY) {
      u32 idx = atomicAdd(counter, 1u);
      uniq[idx] = key;
      payload[h] = idx;
      break;
    }
    if (prev == key) break;
    h = (h + 1) & HMASK;
  }
}

// rank[u] = #{ j : uniq[j] < uniq[u] }  (LDS-tiled pairwise count; U ~ hundreds)
__global__ __launch_bounds__(256) void k_rank(const u64* __restrict__ uniq,
                                              const u32* __restrict__ counter,
                                              u32* __restrict__ RANK){
  __shared__ u64 chunk[2048];
  u32 U = *counter;
  int u = blockIdx.x*256 + threadIdx.x;
  u64 mykey = (u < (int)U) ? uniq[u] : 0;
  u32 cnt = 0;
  for (u32 base = 0; base < U; base += 2048) {
    u32 n = (U - base < 2048u) ? (U - base) : 2048u;
    __syncthreads();
    for (u32 t = threadIdx.x; t < n; t += 256) chunk[t] = uniq[base + t];
    __syncthreads();
    if (u < (int)U)
      for (u32 j = 0; j < n; ++j) cnt += (chunk[j] < mykey) ? 1u : 0u;
  }
  if (u < (int)U) RANK[u] = cnt;
}

__global__ void k_ids(const int* __restrict__ q_data, const u64* __restrict__ KEYT,
                      const u64* __restrict__ htab, const u32* __restrict__ payload,
                      const u32* __restrict__ RANK, float* __restrict__ out_ids){
  int i = blockIdx.x*blockDim.x + threadIdx.x;
  if (i >= NSAMP) return;
  u64 key = KEYT[clampq(q_data[i])];
  u32 h = hash64(key) & HMASK;
  while (htab[h] != key) h = (h + 1) & HMASK;
  out_ids[i] = (float)RANK[payload[h]];   // OUTPUT IS FLOAT32
}

// One workgroup per batch element; thread j owns gate row j (W_hh[j,:] in regs).
__global__ __launch_bounds__(256) void k_lstm(
    const int* __restrict__ q_data, const float* __restrict__ XW,
    const float* __restrict__ W_hh,
    const float* __restrict__ W_pred, const float* __restrict__ b_pred,
    const float* __restrict__ init_h, const float* __restrict__ init_c,
    float* __restrict__ out_pred){
  int b = blockIdx.x, tid = threadIdx.x;
  __shared__ __align__(16) float sh[HH];
  __shared__ float sc[HH];
  __shared__ float sg[4*HH];
  __shared__ float swp[HH];
  __shared__ float sbp;
  float4 whh[HH/4];
  const float4* wrow = (const float4*)(W_hh + tid*HH);
  #pragma unroll
  for (int k4 = 0; k4 < HH/4; ++k4) whh[k4] = wrow[k4];
  if (tid < HH) {
    sh[tid]  = init_h[b*HH + tid];
    sc[tid]  = init_c[b*HH + tid];
    swp[tid] = W_pred[tid];
  }
  if (tid == 0) sbp = b_pred[0];
  __syncthreads();

  int q = clampq(q_data[b*SS + 0]);
  float xw = XW[q*256 + tid];
  for (int s = 0; s < SS; ++s) {
    float xw_next = 0.f;
    if (s + 1 < SS) {
      int qn = clampq(q_data[b*SS + s + 1]);
      xw_next = XW[qn*256 + tid];          // prefetch next step's gate input
    }
    float acc = xw;
    const float4* h4 = (const float4*)sh;
    #pragma unroll
    for (int k4 = 0; k4 < HH/4; ++k4) {
      float4 hv = h4[k4];
      acc += whh[k4].x*hv.x + whh[k4].y*hv.y + whh[k4].z*hv.z + whh[k4].w*hv.w;
    }
    sg[tid] = acc;
    __syncthreads();
    if (tid < HH) {
      float ii = sg[tid], ff = sg[HH+tid], gg = sg[2*HH+tid], oo = sg[3*HH+tid];
      float cc = sigm(ff)*sc[tid] + sigm(ii)*tanhf(gg);
      float hn = sigm(oo)*tanhf(cc);
      sc[tid] = cc;
      sh[tid] = hn;
      float t = hn * swp[tid];
      #pragma unroll
      for (int off = 32; off > 0; off >>= 1) t += __shfl_down(t, off, 64);
      if (tid == 0) out_pred[b*SS + s] = sigm(t + sbp);   // OUTPUT IS FLOAT32
    }
    __syncthreads();
    xw = xw_next;
  }
}

extern "C" void kernel_launch(void* const* d_in, const int* in_sizes, int n_in,
                              void* d_out, int out_size, void* d_ws, size_t ws_size,
                              hipStream_t stream) {
  const int*   q_data  = (const int*)d_in[0];
  const float* emb     = (const float*)d_in[1];
  const float* keym    = (const float*)d_in[2];
  const float* val     = (const float*)d_in[3];
  const float* W_ih    = (const float*)d_in[4];
  const float* W_hh    = (const float*)d_in[5];
  const float* b_ih    = (const float*)d_in[6];
  const float* b_hh    = (const float*)d_in[7];
  const float* W_pred  = (const float*)d_in[8];
  const float* b_pred  = (const float*)d_in[9];
  const float* init_h  = (const float*)d_in[10];
  const float* init_c  = (const float*)d_in[11];

  char* ws = (char*)d_ws;                    // 10.87 MB total (R2-proven footprint)
  float* XW      = (float*)(ws + 0);         // 10,241,024
  float* VW      = (float*)(ws + 10241024);  // 32,768
  u64*  KEYT     = (u64*) (ws + 10273792);   // 80,128
  u64*  uniq     = (u64*) (ws + 10353920);   // 80,128
  u32*  RANK     = (u32*) (ws + 10434048);   // 40,192
  u64*  htab     = (u64*) (ws + 10474240);   // 262,144
  u32*  payload  = (u32*) (ws + 10736384);   // 131,072
  u32*  counter  = (u32*) (ws + 10867456);   // 4

  float* out_pred = (float*)d_out;           // reference output dtype: float32
  float* out_ids  = out_pred + NSAMP;

  hipLaunchKernelGGL(k_vw,    dim3((MM*256+255)/256), dim3(256), 0, stream, val, W_ih, VW);
  hipLaunchKernelGGL(k_init,  dim3(HSIZE/256), dim3(256), 0, stream, htab, counter);
  hipLaunchKernelGGL(k_table, dim3(NROWS), dim3(256), 0, stream,
                     emb, keym, W_ih, b_ih, b_hh, VW, XW, KEYT);
  hipLaunchKernelGGL(k_insert,dim3((NSAMP+255)/256), dim3(256), 0, stream,
                     q_data, KEYT, htab, payload, counter, uniq);
  hipLaunchKernelGGL(k_rank,  dim3((NROWS+255)/256), dim3(256), 0, stream, uniq, counter, RANK);
  hipLaunchKernelGGL(k_ids,   dim3((NSAMP+255)/256), dim3(256), 0, stream,
                     q_data, KEYT, htab, payload, RANK, out_ids);
  hipLaunchKernelGGL(k_lstm,  dim3(BB), dim3(256), 0, stream,
                     q_data, XW, W_hh, W_pred, b_pred, init_h, init_c, out_pred);
}

// Round 8
// 554.156 us; speedup vs baseline: 2.0365x; 2.0365x over previous
//
#include <hip/hip_runtime.h>

#define BB 256
#define SS 200
#define MM 32
#define KDIM 128
#define VDIM 256
#define QDIM 128
#define HH 64
#define NROWS 10001
#define NSAMP (BB*SS)
#define INDIM (VDIM+QDIM)
#define DHS 8192
#define DHMASK (DHS-1)

typedef unsigned long long u64;
typedef unsigned int u32;

__device__ __forceinline__ float sigm(float x){ return 1.0f/(1.0f+expf(-x)); }
__device__ __forceinline__ int clampq(int q){ return q < 0 ? 0 : (q > NROWS-1 ? NROWS-1 : q); }

__device__ __forceinline__ u32 hash64(u64 x){
  x ^= x >> 33; x *= 0xff51afd7ed558ccdULL;
  x ^= x >> 33; x *= 0xc4ceb9fe1a85ec53ULL;
  x ^= x >> 33;
  return (u32)x;
}

// VW[m][j] = sum_v value_mem[m,v] * W_ih[j,v]   (read-part of W_ih)
__global__ void k_vw(const float* __restrict__ val, const float* __restrict__ W_ih,
                     float* __restrict__ VW){
  int t = blockIdx.x*blockDim.x + threadIdx.x;
  if (t >= MM*256) return;
  int m = t >> 8, j = t & 255;
  float acc = 0.f;
  for (int v = 0; v < VDIM; ++v)
    acc += val[m*VDIM+v] * W_ih[j*INDIM+v];
  VW[m*256+j] = acc;
}

__global__ void k_init(u32* __restrict__ present){
  int t = blockIdx.x*blockDim.x + threadIdx.x;
  if (t < NROWS) present[t] = 0u;
}

// Per embedding row n: cw = softmax(emb_n . K^T); trit key (reference packing:
// kh = sum iv[0:16]*3^m LSB-first, kl likewise; order key = kh*3^16 + kl);
// XW[n,j] = cw.VW[:,j] + emb_n.Wq[j,:] + b_ih[j]+b_hh[j]
__global__ __launch_bounds__(256) void k_table(
    const float* __restrict__ emb, const float* __restrict__ key_mem,
    const float* __restrict__ W_ih, const float* __restrict__ b_ih,
    const float* __restrict__ b_hh, const float* __restrict__ VW,
    float* __restrict__ XW, u64* __restrict__ KEYT){
  int n = blockIdx.x, tid = threadIdx.x;
  __shared__ float se[QDIM];
  __shared__ float slog[MM];
  __shared__ float scw[MM];
  __shared__ float svw[MM*256];
  if (tid < QDIM) se[tid] = emb[n*QDIM + tid];
  for (int t = tid; t < MM*256; t += 256) svw[t] = VW[t];
  __syncthreads();
  if (tid < MM) {
    float acc = 0.f;
    for (int d = 0; d < KDIM; ++d) acc += se[d]*key_mem[tid*KDIM+d];
    slog[tid] = acc;
  }
  __syncthreads();
  if (tid == 0) {
    float mx = slog[0];
    #pragma unroll
    for (int m = 1; m < MM; ++m) mx = fmaxf(mx, slog[m]);
    float sum = 0.f;
    #pragma unroll
    for (int m = 0; m < MM; ++m) { float e = expf(slog[m]-mx); scw[m] = e; sum += e; }
    int iv[MM];
    #pragma unroll
    for (int m = 0; m < MM; ++m) {
      float cw = scw[m]/sum; scw[m] = cw;
      float w = fminf((cw - 0.075f)/0.013f, (1.0f - cw)/0.912f);
      w = fmaxf(w, 0.0f);
      iv[m] = (w >= 0.6f) ? 2 : ((w >= 0.1f) ? 1 : 0);
    }
    u64 kh = 0, kl = 0, p = 1;
    #pragma unroll
    for (int m = 0; m < 16; ++m) { kh += (u64)iv[m]*p; p *= 3ULL; }
    p = 1;
    #pragma unroll
    for (int m = 16; m < 32; ++m) { kl += (u64)iv[m]*p; p *= 3ULL; }
    KEYT[n] = kh*43046721ULL + kl;   // 3^16: ascending == lexsort((kl,kh))
  }
  __syncthreads();
  float acc = b_ih[tid] + b_hh[tid];
  #pragma unroll
  for (int m = 0; m < MM; ++m) acc += scw[m]*svw[m*256+tid];
  const float* wrow = W_ih + tid*INDIM + VDIM;
  for (int d = 0; d < QDIM; ++d) acc += se[d]*wrow[d];
  XW[n*256 + tid] = acc;
}

// mark which q rows occur (plain stores; same-address stores are benign)
__global__ void k_mark(const int* __restrict__ q_data, u32* __restrict__ present){
  int i = blockIdx.x*blockDim.x + threadIdx.x;
  if (i < NSAMP) present[clampq(q_data[i])] = 1u;
}

// single-workgroup LDS-hash dedup of present rows' keys (no global atomic storms)
__global__ __launch_bounds__(1024) void k_dedup(
    const u32* __restrict__ present, const u64* __restrict__ KEYT,
    u32* __restrict__ g_htab, u32* __restrict__ g_pay,
    u32* __restrict__ counter, u64* __restrict__ uniq){
  __shared__ u32 sh_tab[DHS];
  __shared__ u32 sh_pay[DHS];
  __shared__ u32 sh_cnt;
  int tid = threadIdx.x;
  for (int i = tid; i < DHS; i += 1024) sh_tab[i] = 0u;
  if (tid == 0) sh_cnt = 0u;
  __syncthreads();
  for (int n = tid; n < NROWS; n += 1024) {
    if (!present[n]) continue;
    u64 key = KEYT[n];
    u32 h = hash64(key) & DHMASK;
    while (true) {
      u32 cur = sh_tab[h];                      // read-first: claimed slots cost no atomic
      if (cur != 0u) {
        if (KEYT[cur-1u] == key) break;         // duplicate
        h = (h + 1) & DHMASK; continue;
      }
      u32 prev = atomicCAS(&sh_tab[h], 0u, (u32)(n + 1));
      if (prev == 0u) {                         // claimed
        u32 idx = atomicAdd(&sh_cnt, 1u);
        uniq[idx] = key;
        sh_pay[h] = idx;
        break;
      }
      if (KEYT[prev-1u] == key) break;          // lost race to same key
      h = (h + 1) & DHMASK;
    }
  }
  __syncthreads();
  for (int i = tid; i < DHS; i += 1024) {
    u32 v = sh_tab[i];
    g_htab[i] = v;
    g_pay[i]  = v ? sh_pay[i] : 0u;
  }
  if (tid == 0) *counter = sh_cnt;
}

// rank[u] = #{ j : uniq[j] < uniq[u] }  (U ~ hundreds)
__global__ __launch_bounds__(256) void k_rank(const u64* __restrict__ uniq,
                                              const u32* __restrict__ counter,
                                              u32* __restrict__ RANK){
  __shared__ u64 chunk[2048];
  u32 U = *counter;
  int u = blockIdx.x*256 + threadIdx.x;
  u64 mykey = (u < (int)U) ? uniq[u] : 0;
  u32 cnt = 0;
  for (u32 base = 0; base < U; base += 2048) {
    u32 n = (U - base < 2048u) ? (U - base) : 2048u;
    __syncthreads();
    for (u32 t = threadIdx.x; t < n; t += 256) chunk[t] = uniq[base + t];
    __syncthreads();
    if (u < (int)U)
      for (u32 j = 0; j < n; ++j) cnt += (chunk[j] < mykey) ? 1u : 0u;
  }
  if (u < (int)U) RANK[u] = cnt;
}

// per present row: rank via read-only hash probes
__global__ void k_qrank(const u32* __restrict__ present, const u64* __restrict__ KEYT,
                        const u32* __restrict__ g_htab, const u32* __restrict__ g_pay,
                        const u32* __restrict__ RANK, u32* __restrict__ RANKQ){
  int n = blockIdx.x*blockDim.x + threadIdx.x;
  if (n >= NROWS || !present[n]) return;
  u64 key = KEYT[n];
  u32 h = hash64(key) & DHMASK;
  while (true) {
    u32 cur = g_htab[h];
    if (cur != 0u && KEYT[cur-1u] == key) { RANKQ[n] = RANK[g_pay[h]]; return; }
    h = (h + 1) & DHMASK;
  }
}

// pure gather
__global__ void k_ids(const int* __restrict__ q_data, const u32* __restrict__ RANKQ,
                      float* __restrict__ out_ids){
  int i = blockIdx.x*blockDim.x + threadIdx.x;
  if (i >= NSAMP) return;
  out_ids[i] = (float)RANKQ[clampq(q_data[i])];
}

// One workgroup per batch element; thread j owns gate row j (W_hh[j,:] in regs).
__global__ __launch_bounds__(256) void k_lstm(
    const int* __restrict__ q_data, const float* __restrict__ XW,
    const float* __restrict__ W_hh,
    const float* __restrict__ W_pred, const float* __restrict__ b_pred,
    const float* __restrict__ init_h, const float* __restrict__ init_c,
    float* __restrict__ out_pred){
  int b = blockIdx.x, tid = threadIdx.x;
  __shared__ __align__(16) float sh[HH];
  __shared__ float sc[HH];
  __shared__ float sg[4*HH];
  __shared__ float swp[HH];
  __shared__ float sbp;
  float4 whh[HH/4];
  const float4* wrow = (const float4*)(W_hh + tid*HH);
  #pragma unroll
  for (int k4 = 0; k4 < HH/4; ++k4) whh[k4] = wrow[k4];
  if (tid < HH) {
    sh[tid]  = init_h[b*HH + tid];
    sc[tid]  = init_c[b*HH + tid];
    swp[tid] = W_pred[tid];
  }
  if (tid == 0) sbp = b_pred[0];
  __syncthreads();

  int q = clampq(q_data[b*SS + 0]);
  float xw = XW[q*256 + tid];
  for (int s = 0; s < SS; ++s) {
    float xw_next = 0.f;
    if (s + 1 < SS) {
      int qn = clampq(q_data[b*SS + s + 1]);
      xw_next = XW[qn*256 + tid];          // prefetch next step's gate input
    }
    float acc = xw;
    const float4* h4 = (const float4*)sh;
    #pragma unroll
    for (int k4 = 0; k4 < HH/4; ++k4) {
      float4 hv = h4[k4];
      acc += whh[k4].x*hv.x + whh[k4].y*hv.y + whh[k4].z*hv.z + whh[k4].w*hv.w;
    }
    sg[tid] = acc;
    __syncthreads();
    if (tid < HH) {
      float ii = sg[tid], ff = sg[HH+tid], gg = sg[2*HH+tid], oo = sg[3*HH+tid];
      float cc = sigm(ff)*sc[tid] + sigm(ii)*tanhf(gg);
      float hn = sigm(oo)*tanhf(cc);
      sc[tid] = cc;
      sh[tid] = hn;
      float t = hn * swp[tid];
      #pragma unroll
      for (int off = 32; off > 0; off >>= 1) t += __shfl_down(t, off, 64);
      if (tid == 0) out_pred[b*SS + s] = sigm(t + sbp);
    }
    __syncthreads();
    xw = xw_next;
  }
}

extern "C" void kernel_launch(void* const* d_in, const int* in_sizes, int n_in,
                              void* d_out, int out_size, void* d_ws, size_t ws_size,
                              hipStream_t stream) {
  const int*   q_data  = (const int*)d_in[0];
  const float* emb     = (const float*)d_in[1];
  const float* keym    = (const float*)d_in[2];
  const float* val     = (const float*)d_in[3];
  const float* W_ih    = (const float*)d_in[4];
  const float* W_hh    = (const float*)d_in[5];
  const float* b_ih    = (const float*)d_in[6];
  const float* b_hh    = (const float*)d_in[7];
  const float* W_pred  = (const float*)d_in[8];
  const float* b_pred  = (const float*)d_in[9];
  const float* init_h  = (const float*)d_in[10];
  const float* init_c  = (const float*)d_in[11];

  char* ws = (char*)d_ws;
  float* XW      = (float*)(ws + 0);          // 10,241,024
  float* VW      = (float*)(ws + 10241024);   // 32,768
  u64*  KEYT     = (u64*) (ws + 10273792);    // 80,128
  u64*  uniq     = (u64*) (ws + 10353920);    // 80,128
  u32*  RANK     = (u32*) (ws + 10434048);    // 40,192
  u32*  g_htab   = (u32*) (ws + 10474240);    // 32,768
  u32*  g_pay    = (u32*) (ws + 10507008);    // 32,768
  u32*  counter  = (u32*) (ws + 10539776);    // 64 (pad)
  u32*  present  = (u32*) (ws + 10539840);    // 40,064
  u32*  RANKQ    = (u32*) (ws + 10579904);    // 40,064

  float* out_pred = (float*)d_out;            // reference output dtype: float32
  float* out_ids  = out_pred + NSAMP;

  hipLaunchKernelGGL(k_vw,    dim3((MM*256+255)/256), dim3(256), 0, stream, val, W_ih, VW);
  hipLaunchKernelGGL(k_init,  dim3((NROWS+255)/256), dim3(256), 0, stream, present);
  hipLaunchKernelGGL(k_table, dim3(NROWS), dim3(256), 0, stream,
                     emb, keym, W_ih, b_ih, b_hh, VW, XW, KEYT);
  hipLaunchKernelGGL(k_mark,  dim3((NSAMP+255)/256), dim3(256), 0, stream, q_data, present);
  hipLaunchKernelGGL(k_dedup, dim3(1), dim3(1024), 0, stream,
                     present, KEYT, g_htab, g_pay, counter, uniq);
  hipLaunchKernelGGL(k_rank,  dim3((NROWS+255)/256), dim3(256), 0, stream, uniq, counter, RANK);
  hipLaunchKernelGGL(k_qrank, dim3((NROWS+255)/256), dim3(256), 0, stream,
                     present, KEYT, g_htab, g_pay, RANK, RANKQ);
  hipLaunchKernelGGL(k_ids,   dim3((NSAMP+255)/256), dim3(256), 0, stream, q_data, RANKQ, out_ids);
  hipLaunchKernelGGL(k_lstm,  dim3(BB), dim3(256), 0, stream,
                     q_data, XW, W_hh, W_pred, b_pred, init_h, init_c, out_pred);
}

// Round 10
// 529.065 us; speedup vs baseline: 2.1331x; 1.0474x over previous
//
#include <hip/hip_runtime.h>

#define BB 256
#define SS 200
#define MM 32
#define KDIM 128
#define VDIM 256
#define QDIM 128
#define HH 64
#define NROWS 10001
#define NSAMP (BB*SS)
#define INDIM (VDIM+QDIM)
#define DHS 8192
#define DHMASK (DHS-1)

typedef unsigned long long u64;
typedef unsigned int u32;

__device__ __forceinline__ float sigm(float x){ return 1.0f/(1.0f+expf(-x)); }
__device__ __forceinline__ int clampq(int q){ return q < 0 ? 0 : (q > NROWS-1 ? NROWS-1 : q); }

__device__ __forceinline__ u32 hash64(u64 x){
  x ^= x >> 33; x *= 0xff51afd7ed558ccdULL;
  x ^= x >> 33; x *= 0xc4ceb9fe1a85ec53ULL;
  x ^= x >> 33;
  return (u32)x;
}

// VW[m][j] = sum_v value_mem[m,v] * W_ih[j,v]   (read-part of W_ih)
__global__ void k_vw(const float* __restrict__ val, const float* __restrict__ W_ih,
                     float* __restrict__ VW){
  int t = blockIdx.x*blockDim.x + threadIdx.x;
  if (t >= MM*256) return;
  int m = t >> 8, j = t & 255;
  float acc = 0.f;
  for (int v = 0; v < VDIM; ++v)
    acc += val[m*VDIM+v] * W_ih[j*INDIM+v];
  VW[m*256+j] = acc;
}

__global__ void k_init(u32* __restrict__ present){
  int t = blockIdx.x*blockDim.x + threadIdx.x;
  if (t < NROWS) present[t] = 0u;
}

// Per embedding row n: cw = softmax(emb_n . K^T); trit key (reference packing);
// gate-input row stored INTERLEAVED with stride 256: XW4[n*256 + 4*unit + gate]
__global__ __launch_bounds__(256) void k_table(
    const float* __restrict__ emb, const float* __restrict__ key_mem,
    const float* __restrict__ W_ih, const float* __restrict__ b_ih,
    const float* __restrict__ b_hh, const float* __restrict__ VW,
    float* __restrict__ XW4, u64* __restrict__ KEYT){
  int n = blockIdx.x, tid = threadIdx.x;
  __shared__ float se[QDIM];
  __shared__ float slog[MM];
  __shared__ float scw[MM];
  if (tid < QDIM) se[tid] = emb[n*QDIM + tid];
  __syncthreads();
  if (tid < MM) {
    float acc = 0.f;
    for (int d = 0; d < KDIM; ++d) acc += se[d]*key_mem[tid*KDIM+d];
    slog[tid] = acc;
  }
  __syncthreads();
  if (tid == 0) {
    float mx = slog[0];
    #pragma unroll
    for (int m = 1; m < MM; ++m) mx = fmaxf(mx, slog[m]);
    float sum = 0.f;
    #pragma unroll
    for (int m = 0; m < MM; ++m) { float e = expf(slog[m]-mx); scw[m] = e; sum += e; }
    int iv[MM];
    #pragma unroll
    for (int m = 0; m < MM; ++m) {
      float cw = scw[m]/sum; scw[m] = cw;
      float w = fminf((cw - 0.075f)/0.013f, (1.0f - cw)/0.912f);
      w = fmaxf(w, 0.0f);
      iv[m] = (w >= 0.6f) ? 2 : ((w >= 0.1f) ? 1 : 0);
    }
    u64 kh = 0, kl = 0, p = 1;
    #pragma unroll
    for (int m = 0; m < 16; ++m) { kh += (u64)iv[m]*p; p *= 3ULL; }
    p = 1;
    #pragma unroll
    for (int m = 16; m < 32; ++m) { kl += (u64)iv[m]*p; p *= 3ULL; }
    KEYT[n] = kh*43046721ULL + kl;   // 3^16: ascending == lexsort((kl,kh))
  }
  __syncthreads();
  float acc = b_ih[tid] + b_hh[tid];
  #pragma unroll
  for (int m = 0; m < MM; ++m) acc += scw[m]*VW[m*256+tid];   // coalesced L2 reads
  const float* wrow = W_ih + tid*INDIM + VDIM;
  for (int d = 0; d < QDIM; ++d) acc += se[d]*wrow[d];
  XW4[n*256 + 4*(tid & 63) + (tid >> 6)] = acc;   // stride 256 (4 gates x 64 units)
}

// mark which q rows occur (plain stores; same-address stores are benign)
__global__ void k_mark(const int* __restrict__ q_data, u32* __restrict__ present){
  int i = blockIdx.x*blockDim.x + threadIdx.x;
  if (i < NSAMP) present[clampq(q_data[i])] = 1u;
}

// single-workgroup LDS-hash dedup of present rows' keys
__global__ __launch_bounds__(1024) void k_dedup(
    const u32* __restrict__ present, const u64* __restrict__ KEYT,
    u32* __restrict__ g_htab, u32* __restrict__ g_pay,
    u32* __restrict__ counter, u64* __restrict__ uniq){
  __shared__ u32 sh_tab[DHS];
  __shared__ u32 sh_pay[DHS];
  __shared__ u32 sh_cnt;
  int tid = threadIdx.x;
  for (int i = tid; i < DHS; i += 1024) sh_tab[i] = 0u;
  if (tid == 0) sh_cnt = 0u;
  __syncthreads();
  for (int n = tid; n < NROWS; n += 1024) {
    if (!present[n]) continue;
    u64 key = KEYT[n];
    u32 h = hash64(key) & DHMASK;
    while (true) {
      u32 cur = sh_tab[h];
      if (cur != 0u) {
        if (KEYT[cur-1u] == key) break;
        h = (h + 1) & DHMASK; continue;
      }
      u32 prev = atomicCAS(&sh_tab[h], 0u, (u32)(n + 1));
      if (prev == 0u) {
        u32 idx = atomicAdd(&sh_cnt, 1u);
        uniq[idx] = key;
        sh_pay[h] = idx;
        break;
      }
      if (KEYT[prev-1u] == key) break;
      h = (h + 1) & DHMASK;
    }
  }
  __syncthreads();
  for (int i = tid; i < DHS; i += 1024) {
    u32 v = sh_tab[i];
    g_htab[i] = v;
    g_pay[i]  = v ? sh_pay[i] : 0u;
  }
  if (tid == 0) *counter = sh_cnt;
}

// rank[u] = #{ j : uniq[j] < uniq[u] }
__global__ __launch_bounds__(256) void k_rank(const u64* __restrict__ uniq,
                                              const u32* __restrict__ counter,
                                              u32* __restrict__ RANK){
  __shared__ u64 chunk[2048];
  u32 U = *counter;
  int u = blockIdx.x*256 + threadIdx.x;
  u64 mykey = (u < (int)U) ? uniq[u] : 0;
  u32 cnt = 0;
  for (u32 base = 0; base < U; base += 2048) {
    u32 n = (U - base < 2048u) ? (U - base) : 2048u;
    __syncthreads();
    for (u32 t = threadIdx.x; t < n; t += 256) chunk[t] = uniq[base + t];
    __syncthreads();
    if (u < (int)U)
      for (u32 j = 0; j < n; ++j) cnt += (chunk[j] < mykey) ? 1u : 0u;
  }
  if (u < (int)U) RANK[u] = cnt;
}

// per present row: rank via read-only hash probes
__global__ void k_qrank(const u32* __restrict__ present, const u64* __restrict__ KEYT,
                        const u32* __restrict__ g_htab, const u32* __restrict__ g_pay,
                        const u32* __restrict__ RANK, u32* __restrict__ RANKQ){
  int n = blockIdx.x*blockDim.x + threadIdx.x;
  if (n >= NROWS || !present[n]) return;
  u64 key = KEYT[n];
  u32 h = hash64(key) & DHMASK;
  while (true) {
    u32 cur = g_htab[h];
    if (cur != 0u && KEYT[cur-1u] == key) { RANKQ[n] = RANK[g_pay[h]]; return; }
    h = (h + 1) & DHMASK;
  }
}

__global__ void k_ids(const int* __restrict__ q_data, const u32* __restrict__ RANKQ,
                      float* __restrict__ out_ids){
  int i = blockIdx.x*blockDim.x + threadIdx.x;
  if (i >= NSAMP) return;
  out_ids[i] = (float)RANKQ[clampq(q_data[i])];
}

// Wave-local LSTM: one 64-lane wave per batch element. Lane k owns hidden unit k
// and its 4 W_hh rows in registers. NO barriers in the step loop -> the 4-deep
// XW4 prefetch stays in flight (vmcnt(N), not barrier-drained).
__global__ __launch_bounds__(64, 1) void k_lstm(
    const int* __restrict__ q_data, const float* __restrict__ XW4,
    const float* __restrict__ W_hh,
    const float* __restrict__ W_pred, const float* __restrict__ b_pred,
    const float* __restrict__ init_h, const float* __restrict__ init_c,
    float* __restrict__ out_pred){
  const int b = blockIdx.x, k = threadIdx.x;
  __shared__ float hbuf[HH*(SS+1)];   // stride 201: conflict-free writes & reads
  __shared__ float swp[HH];
  __shared__ int   sq[SS];
  for (int s = k; s < SS; s += HH) sq[s] = clampq(q_data[b*SS + s]);
  swp[k] = W_pred[k];
  float wi[HH], wf[HH], wg[HH], wo[HH];
  {
    const float4* r0 = (const float4*)(W_hh + (size_t)(0*HH + k)*HH);
    const float4* r1 = (const float4*)(W_hh + (size_t)(1*HH + k)*HH);
    const float4* r2 = (const float4*)(W_hh + (size_t)(2*HH + k)*HH);
    const float4* r3 = (const float4*)(W_hh + (size_t)(3*HH + k)*HH);
    #pragma unroll
    for (int j4 = 0; j4 < HH/4; ++j4) {
      float4 a = r0[j4], bq = r1[j4], cq = r2[j4], dq = r3[j4];
      wi[4*j4+0]=a.x;  wi[4*j4+1]=a.y;  wi[4*j4+2]=a.z;  wi[4*j4+3]=a.w;
      wf[4*j4+0]=bq.x; wf[4*j4+1]=bq.y; wf[4*j4+2]=bq.z; wf[4*j4+3]=bq.w;
      wg[4*j4+0]=cq.x; wg[4*j4+1]=cq.y; wg[4*j4+2]=cq.z; wg[4*j4+3]=cq.w;
      wo[4*j4+0]=dq.x; wo[4*j4+1]=dq.y; wo[4*j4+2]=dq.z; wo[4*j4+3]=dq.w;
    }
  }
  float h = init_h[b*HH + k];
  float c = init_c[b*HH + k];
  float bp = b_pred[0];
  __syncthreads();            // covers sq/swp (outside step loop)

  float4 pf[4];
  #pragma unroll
  for (int j = 0; j < 4; ++j)
    pf[j] = *(const float4*)(XW4 + (size_t)sq[j]*256 + 4*k);

  for (int sb = 0; sb < SS; sb += 4) {
    #pragma unroll
    for (int j = 0; j < 4; ++j) {
      const int s = sb + j;
      float4 xw = pf[j];
      int sn = s + 4; if (sn >= SS) sn = SS - 1;
      pf[j] = *(const float4*)(XW4 + (size_t)sq[sn]*256 + 4*k);  // prefetch s+4
      float ai = xw.x, af = xw.y, ag = xw.z, ao = xw.w;
      #pragma unroll
      for (int jj = 0; jj < HH; ++jj) {
        float hj = __uint_as_float(__builtin_amdgcn_readlane(__float_as_uint(h), jj));
        ai += wi[jj]*hj; af += wf[jj]*hj; ag += wg[jj]*hj; ao += wo[jj]*hj;
      }
      c = sigm(af)*c + sigm(ai)*tanhf(ag);
      h = sigm(ao)*tanhf(c);
      hbuf[k*(SS+1) + s] = h;   // off-path store for deferred pred
    }
  }
  __syncthreads();            // hbuf visible (outside step loop)
  #pragma unroll
  for (int cc = 0; cc < 4; ++cc) {
    int s = cc*HH + k;
    if (s < SS) {
      float acc = 0.f;
      #pragma unroll 16
      for (int kk = 0; kk < HH; ++kk) acc += hbuf[kk*(SS+1) + s] * swp[kk];
      out_pred[b*SS + s] = sigm(acc + bp);
    }
  }
}

extern "C" void kernel_launch(void* const* d_in, const int* in_sizes, int n_in,
                              void* d_out, int out_size, void* d_ws, size_t ws_size,
                              hipStream_t stream) {
  const int*   q_data  = (const int*)d_in[0];
  const float* emb     = (const float*)d_in[1];
  const float* keym    = (const float*)d_in[2];
  const float* val     = (const float*)d_in[3];
  const float* W_ih    = (const float*)d_in[4];
  const float* W_hh    = (const float*)d_in[5];
  const float* b_ih    = (const float*)d_in[6];
  const float* b_hh    = (const float*)d_in[7];
  const float* W_pred  = (const float*)d_in[8];
  const float* b_pred  = (const float*)d_in[9];
  const float* init_h  = (const float*)d_in[10];
  const float* init_c  = (const float*)d_in[11];

  char* ws = (char*)d_ws;
  float* XW4     = (float*)(ws + 0);          // 10,241,024  (NROWS*256 floats)
  float* VW      = (float*)(ws + 10241024);   // 32,768
  u64*  KEYT     = (u64*) (ws + 10273792);    // 80,128
  u64*  uniq     = (u64*) (ws + 10353920);    // 80,128
  u32*  RANK     = (u32*) (ws + 10434048);    // 40,192
  u32*  g_htab   = (u32*) (ws + 10474240);    // 32,768
  u32*  g_pay    = (u32*) (ws + 10507008);    // 32,768
  u32*  counter  = (u32*) (ws + 10539776);    // 64 (pad)
  u32*  present  = (u32*) (ws + 10539840);    // 40,064
  u32*  RANKQ    = (u32*) (ws + 10579904);    // 40,064

  float* out_pred = (float*)d_out;            // float32 outputs
  float* out_ids  = out_pred + NSAMP;

  hipLaunchKernelGGL(k_vw,    dim3((MM*256+255)/256), dim3(256), 0, stream, val, W_ih, VW);
  hipLaunchKernelGGL(k_init,  dim3((NROWS+255)/256), dim3(256), 0, stream, present);
  hipLaunchKernelGGL(k_table, dim3(NROWS), dim3(256), 0, stream,
                     emb, keym, W_ih, b_ih, b_hh, VW, XW4, KEYT);
  hipLaunchKernelGGL(k_mark,  dim3((NSAMP+255)/256), dim3(256), 0, stream, q_data, present);
  hipLaunchKernelGGL(k_dedup, dim3(1), dim3(1024), 0, stream,
                     present, KEYT, g_htab, g_pay, counter, uniq);
  hipLaunchKernelGGL(k_rank,  dim3((NROWS+255)/256), dim3(256), 0, stream, uniq, counter, RANK);
  hipLaunchKernelGGL(k_qrank, dim3((NROWS+255)/256), dim3(256), 0, stream,
                     present, KEYT, g_htab, g_pay, RANK, RANKQ);
  hipLaunchKernelGGL(k_ids,   dim3((NSAMP+255)/256), dim3(256), 0, stream, q_data, RANKQ, out_ids);
  hipLaunchKernelGGL(k_lstm,  dim3(BB), dim3(64), 0, stream,
                     q_data, XW4, W_hh, W_pred, b_pred, init_h, init_c, out_pred);
}

// Round 11
// 333.324 us; speedup vs baseline: 3.3857x; 1.5872x over previous
//
#include <hip/hip_runtime.h>

#define BB 256
#define SS 200
#define MM 32
#define KDIM 128
#define VDIM 256
#define QDIM 128
#define HH 64
#define NROWS 10001
#define NSAMP (BB*SS)
#define INDIM (VDIM+QDIM)
#define DHS 8192
#define DHMASK (DHS-1)
#define XR 16

typedef unsigned long long u64;
typedef unsigned int u32;

__device__ __forceinline__ float fexp(float x){ return __builtin_amdgcn_exp2f(x * 1.44269504f); }
__device__ __forceinline__ float fsigm(float x){ return __builtin_amdgcn_rcpf(1.f + fexp(-x)); }
__device__ __forceinline__ float ftanh(float x){ return 1.f - 2.f*__builtin_amdgcn_rcpf(1.f + fexp(2.f*x)); }
__device__ __forceinline__ int clampq(int q){ return q < 0 ? 0 : (q > NROWS-1 ? NROWS-1 : q); }

__device__ __forceinline__ u32 hash64(u64 x){
  x ^= x >> 33; x *= 0xff51afd7ed558ccdULL;
  x ^= x >> 33; x *= 0xc4ceb9fe1a85ec53ULL;
  x ^= x >> 33;
  return (u32)x;
}

__device__ __forceinline__ u64 shflx64(u64 v, int m){
  int lo = __shfl_xor((int)(u32)v, m, 64);
  int hi = __shfl_xor((int)(u32)(v >> 32), m, 64);
  return ((u64)(u32)hi << 32) | (u32)lo;
}

// transposes: WQT4[(d4*256+j)*4+dd] = W_ih[j][VDIM+4*d4+dd]; KT[d*32+m] = key_mem[m][d]
__global__ void k_tr(const float* __restrict__ W_ih, const float* __restrict__ key_mem,
                     float* __restrict__ WQT4, float* __restrict__ KT){
  int idx = blockIdx.x*256 + threadIdx.x;
  if (idx < 131072) {
    int dd = idx & 3, j = (idx >> 2) & 255, d4 = idx >> 10;
    WQT4[idx] = W_ih[j*INDIM + VDIM + 4*d4 + dd];
  } else {
    int t = idx - 131072;
    if (t < 4096) { int m = t & 31, d = t >> 5; KT[t] = key_mem[m*KDIM + d]; }
  }
}

// VW[m][j] = sum_v value_mem[m,v] * W_ih[j,v]
__global__ void k_vw(const float* __restrict__ val, const float* __restrict__ W_ih,
                     float* __restrict__ VW){
  int t = blockIdx.x*blockDim.x + threadIdx.x;
  if (t >= MM*256) return;
  int m = t >> 8, j = t & 255;
  float acc = 0.f;
  for (int v = 0; v < VDIM; ++v)
    acc += val[m*VDIM+v] * W_ih[j*INDIM+v];
  VW[m*256+j] = acc;
}

__global__ void k_init(u32* __restrict__ present){
  int t = blockIdx.x*blockDim.x + threadIdx.x;
  if (t < NROWS) present[t] = 0u;
}

// one WAVE per row: logits (coalesced via KT), shuffle softmax, trit key.
// cw stored overlaid in XW4 rows: CW[n*256 + m], m<32.
__global__ __launch_bounds__(256) void k_attn(
    const float* __restrict__ emb, const float* __restrict__ KT,
    float* __restrict__ CW, u64* __restrict__ KEYT){
  int w = threadIdx.x >> 6, l = threadIdx.x & 63;
  int n = blockIdx.x*4 + w;
  __shared__ float se[4][QDIM];
  bool valid = (n < NROWS);
  if (valid) {
    se[w][l]      = emb[n*QDIM + l];
    se[w][l + 64] = emb[n*QDIM + l + 64];
  }
  __syncthreads();
  int m = l & 31;
  float logit = 0.f;
  if (valid && l < 32)
    for (int d = 0; d < KDIM; ++d) logit += se[w][d] * KT[d*32 + m];
  float mx = logit;
  #pragma unroll
  for (int msk = 16; msk >= 1; msk >>= 1) mx = fmaxf(mx, __shfl_xor(mx, msk, 64));
  float e = (l < 32) ? expf(logit - mx) : 0.f;      // precise expf: trit boundaries
  float sum = e;
  #pragma unroll
  for (int msk = 16; msk >= 1; msk >>= 1) sum += __shfl_xor(sum, msk, 64);
  float cw = e / sum;
  float wv = fminf((cw - 0.075f)/0.013f, (1.0f - cw)/0.912f);
  wv = fmaxf(wv, 0.f);
  int iv = (wv >= 0.6f) ? 2 : ((wv >= 0.1f) ? 1 : 0);
  // key = sum_m iv[m] * 3^(m<16 ? m+16 : m-16)  == kh*3^16 + kl (reference packing)
  int ee = (m < 16) ? m + 16 : m - 16;
  u64 p3 = 1;
  for (int i = 0; i < 31; ++i) if (i < ee) p3 *= 3ULL;
  u64 term = (valid && l < 32) ? (u64)iv * p3 : 0ULL;
  #pragma unroll
  for (int msk = 16; msk >= 1; msk >>= 1) term += shflx64(term, msk);
  if (valid && l < 32) CW[n*256 + m] = cw;
  if (valid && l == 0) KEYT[n] = term;
}

// XW4 row = bias + cw.VW + emb.WqT, tiled GEMM: 16 rows/block, 256 cols (threads)
__global__ __launch_bounds__(256) void k_xw(
    const float* __restrict__ CW, const float* __restrict__ emb,
    const float* __restrict__ VW, const float* __restrict__ WQT4,
    const float* __restrict__ b_ih, const float* __restrict__ b_hh,
    float* __restrict__ XW4){
  int base = blockIdx.x * XR;
  int j = threadIdx.x;
  __shared__ float scw[XR][32];
  __shared__ __align__(16) float ses[XR][QDIM];
  for (int idx = j; idx < XR*32; idx += 256) {
    int r = idx >> 5, m = idx & 31, n = base + r;
    scw[r][m] = (n < NROWS) ? CW[n*256 + m] : 0.f;
  }
  for (int idx = j; idx < XR*QDIM; idx += 256) {
    int r = idx >> 7, d = idx & 127, n = base + r;
    ses[r][d] = (n < NROWS) ? emb[n*QDIM + d] : 0.f;
  }
  __syncthreads();
  float bias = b_ih[j] + b_hh[j];
  float acc[XR];
  #pragma unroll
  for (int r = 0; r < XR; ++r) acc[r] = bias;
  for (int m = 0; m < MM; ++m) {
    float wv = VW[m*256 + j];
    #pragma unroll
    for (int r = 0; r < XR; ++r) acc[r] += scw[r][m] * wv;
  }
  for (int d4 = 0; d4 < QDIM/4; ++d4) {
    float4 wq = *(const float4*)(WQT4 + d4*1024 + j*4);
    #pragma unroll
    for (int r = 0; r < XR; ++r) {
      float4 ev = *(const float4*)(&ses[r][4*d4]);
      acc[r] += ev.x*wq.x + ev.y*wq.y + ev.z*wq.z + ev.w*wq.w;
    }
  }
  int gate = j >> 6, unit = j & 63;
  #pragma unroll
  for (int r = 0; r < XR; ++r)
    if (base + r < NROWS) XW4[(size_t)(base + r)*256 + 4*unit + gate] = acc[r];
}

__global__ void k_mark(const int* __restrict__ q_data, u32* __restrict__ present){
  int i = blockIdx.x*blockDim.x + threadIdx.x;
  if (i < NSAMP) present[clampq(q_data[i])] = 1u;
}

// single-workgroup LDS-hash dedup of present rows' keys
__global__ __launch_bounds__(1024) void k_dedup(
    const u32* __restrict__ present, const u64* __restrict__ KEYT,
    u32* __restrict__ g_htab, u32* __restrict__ g_pay,
    u32* __restrict__ counter, u64* __restrict__ uniq){
  __shared__ u32 sh_tab[DHS];
  __shared__ u32 sh_pay[DHS];
  __shared__ u32 sh_cnt;
  int tid = threadIdx.x;
  for (int i = tid; i < DHS; i += 1024) sh_tab[i] = 0u;
  if (tid == 0) sh_cnt = 0u;
  __syncthreads();
  for (int n = tid; n < NROWS; n += 1024) {
    if (!present[n]) continue;
    u64 key = KEYT[n];
    u32 h = hash64(key) & DHMASK;
    while (true) {
      u32 cur = sh_tab[h];
      if (cur != 0u) {
        if (KEYT[cur-1u] == key) break;
        h = (h + 1) & DHMASK; continue;
      }
      u32 prev = atomicCAS(&sh_tab[h], 0u, (u32)(n + 1));
      if (prev == 0u) {
        u32 idx = atomicAdd(&sh_cnt, 1u);
        uniq[idx] = key;
        sh_pay[h] = idx;
        break;
      }
      if (KEYT[prev-1u] == key) break;
      h = (h + 1) & DHMASK;
    }
  }
  __syncthreads();
  for (int i = tid; i < DHS; i += 1024) {
    u32 v = sh_tab[i];
    g_htab[i] = v;
    g_pay[i]  = v ? sh_pay[i] : 0u;
  }
  if (tid == 0) *counter = sh_cnt;
}

__global__ __launch_bounds__(256) void k_rank(const u64* __restrict__ uniq,
                                              const u32* __restrict__ counter,
                                              u32* __restrict__ RANK){
  __shared__ u64 chunk[2048];
  u32 U = *counter;
  int u = blockIdx.x*256 + threadIdx.x;
  u64 mykey = (u < (int)U) ? uniq[u] : 0;
  u32 cnt = 0;
  for (u32 base = 0; base < U; base += 2048) {
    u32 n = (U - base < 2048u) ? (U - base) : 2048u;
    __syncthreads();
    for (u32 t = threadIdx.x; t < n; t += 256) chunk[t] = uniq[base + t];
    __syncthreads();
    if (u < (int)U)
      for (u32 j = 0; j < n; ++j) cnt += (chunk[j] < mykey) ? 1u : 0u;
  }
  if (u < (int)U) RANK[u] = cnt;
}

__global__ void k_qrank(const u32* __restrict__ present, const u64* __restrict__ KEYT,
                        const u32* __restrict__ g_htab, const u32* __restrict__ g_pay,
                        const u32* __restrict__ RANK, u32* __restrict__ RANKQ){
  int n = blockIdx.x*blockDim.x + threadIdx.x;
  if (n >= NROWS || !present[n]) return;
  u64 key = KEYT[n];
  u32 h = hash64(key) & DHMASK;
  while (true) {
    u32 cur = g_htab[h];
    if (cur != 0u && KEYT[cur-1u] == key) { RANKQ[n] = RANK[g_pay[h]]; return; }
    h = (h + 1) & DHMASK;
  }
}

__global__ void k_ids(const int* __restrict__ q_data, const u32* __restrict__ RANKQ,
                      float* __restrict__ out_ids){
  int i = blockIdx.x*blockDim.x + threadIdx.x;
  if (i >= NSAMP) return;
  out_ids[i] = (float)RANKQ[clampq(q_data[i])];
}

// Wave-local LSTM: one 64-lane wave per batch element; no barriers in step loop.
__global__ __launch_bounds__(64, 1) void k_lstm(
    const int* __restrict__ q_data, const float* __restrict__ XW4,
    const float* __restrict__ W_hh,
    const float* __restrict__ W_pred, const float* __restrict__ b_pred,
    const float* __restrict__ init_h, const float* __restrict__ init_c,
    float* __restrict__ out_pred){
  const int b = blockIdx.x, k = threadIdx.x;
  __shared__ float hbuf[HH*(SS+1)];
  __shared__ float swp[HH];
  __shared__ int   sq[SS];
  for (int s = k; s < SS; s += HH) sq[s] = clampq(q_data[b*SS + s]);
  swp[k] = W_pred[k];
  float wi[HH], wf[HH], wg[HH], wo[HH];
  {
    const float4* r0 = (const float4*)(W_hh + (size_t)(0*HH + k)*HH);
    const float4* r1 = (const float4*)(W_hh + (size_t)(1*HH + k)*HH);
    const float4* r2 = (const float4*)(W_hh + (size_t)(2*HH + k)*HH);
    const float4* r3 = (const float4*)(W_hh + (size_t)(3*HH + k)*HH);
    #pragma unroll
    for (int j4 = 0; j4 < HH/4; ++j4) {
      float4 a = r0[j4], bq = r1[j4], cq = r2[j4], dq = r3[j4];
      wi[4*j4+0]=a.x;  wi[4*j4+1]=a.y;  wi[4*j4+2]=a.z;  wi[4*j4+3]=a.w;
      wf[4*j4+0]=bq.x; wf[4*j4+1]=bq.y; wf[4*j4+2]=bq.z; wf[4*j4+3]=bq.w;
      wg[4*j4+0]=cq.x; wg[4*j4+1]=cq.y; wg[4*j4+2]=cq.z; wg[4*j4+3]=cq.w;
      wo[4*j4+0]=dq.x; wo[4*j4+1]=dq.y; wo[4*j4+2]=dq.z; wo[4*j4+3]=dq.w;
    }
  }
  float h = init_h[b*HH + k];
  float c = init_c[b*HH + k];
  float bp = b_pred[0];
  __syncthreads();

  float4 pf[4];
  #pragma unroll
  for (int j = 0; j < 4; ++j)
    pf[j] = *(const float4*)(XW4 + (size_t)sq[j]*256 + 4*k);

  for (int sb = 0; sb < SS; sb += 4) {
    #pragma unroll
    for (int j = 0; j < 4; ++j) {
      const int s = sb + j;
      float4 xw = pf[j];
      int sn = s + 4; if (sn >= SS) sn = SS - 1;
      pf[j] = *(const float4*)(XW4 + (size_t)sq[sn]*256 + 4*k);
      float ai = xw.x, af = xw.y, ag = xw.z, ao = xw.w;
      #pragma unroll
      for (int jj = 0; jj < HH; ++jj) {
        float hj = __uint_as_float(__builtin_amdgcn_readlane(__float_as_uint(h), jj));
        ai += wi[jj]*hj; af += wf[jj]*hj; ag += wg[jj]*hj; ao += wo[jj]*hj;
      }
      c = fsigm(af)*c + fsigm(ai)*ftanh(ag);
      h = fsigm(ao)*ftanh(c);
      hbuf[k*(SS+1) + s] = h;
    }
  }
  __syncthreads();
  #pragma unroll
  for (int cc = 0; cc < 4; ++cc) {
    int s = cc*HH + k;
    if (s < SS) {
      float acc = 0.f;
      #pragma unroll 16
      for (int kk = 0; kk < HH; ++kk) acc += hbuf[kk*(SS+1) + s] * swp[kk];
      out_pred[b*SS + s] = fsigm(acc + bp);
    }
  }
}

extern "C" void kernel_launch(void* const* d_in, const int* in_sizes, int n_in,
                              void* d_out, int out_size, void* d_ws, size_t ws_size,
                              hipStream_t stream) {
  const int*   q_data  = (const int*)d_in[0];
  const float* emb     = (const float*)d_in[1];
  const float* keym    = (const float*)d_in[2];
  const float* val     = (const float*)d_in[3];
  const float* W_ih    = (const float*)d_in[4];
  const float* W_hh    = (const float*)d_in[5];
  const float* b_ih    = (const float*)d_in[6];
  const float* b_hh    = (const float*)d_in[7];
  const float* W_pred  = (const float*)d_in[8];
  const float* b_pred  = (const float*)d_in[9];
  const float* init_h  = (const float*)d_in[10];
  const float* init_c  = (const float*)d_in[11];

  char* ws = (char*)d_ws;
  float* XW4     = (float*)(ws + 0);          // 10,241,024 (CW overlaid in low 32 floats/row)
  float* VW      = (float*)(ws + 10241024);   // 32,768
  u64*  KEYT     = (u64*) (ws + 10273792);    // 80,128
  u64*  uniq     = (u64*) (ws + 10353920);    // 80,128
  u32*  RANK     = (u32*) (ws + 10434048);    // 40,192
  u32*  g_htab   = (u32*) (ws + 10474240);    // 32,768
  u32*  g_pay    = (u32*) (ws + 10507008);    // 32,768
  u32*  counter  = (u32*) (ws + 10539776);    // 64
  u32*  present  = (u32*) (ws + 10539840);    // 40,064
  u32*  RANKQ    = (u32*) (ws + 10579904);    // 40,064
  float* WQT4    = (float*)(ws + 10619968);   // 524,288
  float* KT      = (float*)(ws + 11144256);   // 16,384
  float* CW      = XW4;                       // overlay: CW[n*256+m]

  float* out_pred = (float*)d_out;
  float* out_ids  = out_pred + NSAMP;

  hipLaunchKernelGGL(k_tr,    dim3(528), dim3(256), 0, stream, W_ih, keym, WQT4, KT);
  hipLaunchKernelGGL(k_vw,    dim3((MM*256+255)/256), dim3(256), 0, stream, val, W_ih, VW);
  hipLaunchKernelGGL(k_init,  dim3((NROWS+255)/256), dim3(256), 0, stream, present);
  hipLaunchKernelGGL(k_attn,  dim3((NROWS+3)/4), dim3(256), 0, stream, emb, KT, CW, KEYT);
  hipLaunchKernelGGL(k_mark,  dim3((NSAMP+255)/256), dim3(256), 0, stream, q_data, present);
  hipLaunchKernelGGL(k_dedup, dim3(1), dim3(1024), 0, stream,
                     present, KEYT, g_htab, g_pay, counter, uniq);
  hipLaunchKernelGGL(k_rank,  dim3((NROWS+255)/256), dim3(256), 0, stream, uniq, counter, RANK);
  hipLaunchKernelGGL(k_qrank, dim3((NROWS+255)/256), dim3(256), 0, stream,
                     present, KEYT, g_htab, g_pay, RANK, RANKQ);
  hipLaunchKernelGGL(k_xw,    dim3((NROWS+XR-1)/XR), dim3(256), 0, stream,
                     CW, emb, VW, WQT4, b_ih, b_hh, XW4);
  hipLaunchKernelGGL(k_ids,   dim3((NSAMP+255)/256), dim3(256), 0, stream, q_data, RANKQ, out_ids);
  hipLaunchKernelGGL(k_lstm,  dim3(BB), dim3(64), 0, stream,
                     q_data, XW4, W_hh, W_pred, b_pred, init_h, init_c, out_pred);
}

// Round 12
// 299.943 us; speedup vs baseline: 3.7625x; 1.1113x over previous
//
#include <hip/hip_runtime.h>

#define BB 256
#define SS 200
#define MM 32
#define KDIM 128
#define VDIM 256
#define QDIM 128
#define HH 64
#define NROWS 10001
#define NSAMP (BB*SS)
#define INDIM (VDIM+QDIM)
#define DHS 8192
#define DHMASK (DHS-1)
#define XR 16
#define CH 50

typedef unsigned long long u64;
typedef unsigned int u32;

__device__ __forceinline__ float fexp(float x){ return __builtin_amdgcn_exp2f(x * 1.44269504f); }
__device__ __forceinline__ float fsigm(float x){ return __builtin_amdgcn_rcpf(1.f + fexp(-x)); }
__device__ __forceinline__ float ftanh(float x){ return 1.f - 2.f*__builtin_amdgcn_rcpf(1.f + fexp(2.f*x)); }
__device__ __forceinline__ int clampq(int q){ return q < 0 ? 0 : (q > NROWS-1 ? NROWS-1 : q); }
__device__ __forceinline__ float rl(float v, int lane){
  return __uint_as_float(__builtin_amdgcn_readlane(__float_as_uint(v), lane));
}

__device__ __forceinline__ u32 hash64(u64 x){
  x ^= x >> 33; x *= 0xff51afd7ed558ccdULL;
  x ^= x >> 33; x *= 0xc4ceb9fe1a85ec53ULL;
  x ^= x >> 33;
  return (u32)x;
}

__device__ __forceinline__ u64 shflx64(u64 v, int m){
  int lo = __shfl_xor((int)(u32)v, m, 64);
  int hi = __shfl_xor((int)(u32)(v >> 32), m, 64);
  return ((u64)(u32)hi << 32) | (u32)lo;
}

// transposes: WQT4[(d4*256+j)*4+dd]=W_ih[j][VDIM+4d4+dd]; KT[d*32+m]=key_mem[m][d];
//             WVT[v*256+j]=W_ih[j][v]
__global__ void k_tr(const float* __restrict__ W_ih, const float* __restrict__ key_mem,
                     float* __restrict__ WQT4, float* __restrict__ KT,
                     float* __restrict__ WVT){
  int idx = blockIdx.x*256 + threadIdx.x;
  if (idx < 131072) {
    int dd = idx & 3, j = (idx >> 2) & 255, d4 = idx >> 10;
    WQT4[idx] = W_ih[j*INDIM + VDIM + 4*d4 + dd];
  } else if (idx < 135168) {
    int t = idx - 131072;
    int m = t & 31, d = t >> 5; KT[t] = key_mem[m*KDIM + d];
  } else {
    int t = idx - 135168;
    if (t < 65536) { int j = t & 255, v = t >> 8; WVT[v*256 + j] = W_ih[j*INDIM + v]; }
  }
}

// VW[m][j] = sum_v val[m][v]*WVT[v][j]  (coalesced)
__global__ __launch_bounds__(256) void k_vw(const float* __restrict__ val,
                                            const float* __restrict__ WVT,
                                            float* __restrict__ VW){
  int m = blockIdx.x, j = threadIdx.x;
  __shared__ float sval[VDIM];
  sval[j] = val[m*VDIM + j];
  __syncthreads();
  float a0=0.f, a1=0.f, a2=0.f, a3=0.f;
  for (int v = 0; v < VDIM; v += 4) {
    a0 += sval[v+0]*WVT[(v+0)*256 + j];
    a1 += sval[v+1]*WVT[(v+1)*256 + j];
    a2 += sval[v+2]*WVT[(v+2)*256 + j];
    a3 += sval[v+3]*WVT[(v+3)*256 + j];
  }
  VW[m*256 + j] = (a0+a1)+(a2+a3);
}

__global__ void k_init(u32* __restrict__ present){
  int t = blockIdx.x*blockDim.x + threadIdx.x;
  if (t < NROWS) present[t] = 0u;
}

// one WAVE per row: logits via KT, shuffle softmax, trit key; CW overlaid in XW4 rows
__global__ __launch_bounds__(256) void k_attn(
    const float* __restrict__ emb, const float* __restrict__ KT,
    float* __restrict__ CW, u64* __restrict__ KEYT){
  int w = threadIdx.x >> 6, l = threadIdx.x & 63;
  int n = blockIdx.x*4 + w;
  __shared__ float se[4][QDIM];
  bool valid = (n < NROWS);
  if (valid) {
    se[w][l]      = emb[n*QDIM + l];
    se[w][l + 64] = emb[n*QDIM + l + 64];
  }
  __syncthreads();
  int m = l & 31;
  float logit = 0.f;
  if (valid && l < 32)
    for (int d = 0; d < KDIM; ++d) logit += se[w][d] * KT[d*32 + m];
  float mx = logit;
  #pragma unroll
  for (int msk = 16; msk >= 1; msk >>= 1) mx = fmaxf(mx, __shfl_xor(mx, msk, 64));
  float e = (l < 32) ? expf(logit - mx) : 0.f;      // precise expf: trit boundaries
  float sum = e;
  #pragma unroll
  for (int msk = 16; msk >= 1; msk >>= 1) sum += __shfl_xor(sum, msk, 64);
  float cw = e / sum;
  float wv = fminf((cw - 0.075f)/0.013f, (1.0f - cw)/0.912f);
  wv = fmaxf(wv, 0.f);
  int iv = (wv >= 0.6f) ? 2 : ((wv >= 0.1f) ? 1 : 0);
  int ee = (m < 16) ? m + 16 : m - 16;   // key = kh*3^16 + kl (reference packing)
  u64 p3 = 1;
  for (int i = 0; i < 31; ++i) if (i < ee) p3 *= 3ULL;
  u64 term = (valid && l < 32) ? (u64)iv * p3 : 0ULL;
  #pragma unroll
  for (int msk = 16; msk >= 1; msk >>= 1) term += shflx64(term, msk);
  if (valid && l < 32) CW[n*256 + m] = cw;
  if (valid && l == 0) KEYT[n] = term;
}

// XW4 row = bias + cw.VW + emb.WqT: 16 rows/block tiled GEMM
__global__ __launch_bounds__(256) void k_xw(
    const float* __restrict__ CW, const float* __restrict__ emb,
    const float* __restrict__ VW, const float* __restrict__ WQT4,
    const float* __restrict__ b_ih, const float* __restrict__ b_hh,
    float* __restrict__ XW4){
  int base = blockIdx.x * XR;
  int j = threadIdx.x;
  __shared__ float scw[XR][32];
  __shared__ __align__(16) float ses[XR][QDIM];
  for (int idx = j; idx < XR*32; idx += 256) {
    int r = idx >> 5, m = idx & 31, n = base + r;
    scw[r][m] = (n < NROWS) ? CW[n*256 + m] : 0.f;
  }
  for (int idx = j; idx < XR*QDIM; idx += 256) {
    int r = idx >> 7, d = idx & 127, n = base + r;
    ses[r][d] = (n < NROWS) ? emb[n*QDIM + d] : 0.f;
  }
  __syncthreads();
  float bias = b_ih[j] + b_hh[j];
  float acc[XR];
  #pragma unroll
  for (int r = 0; r < XR; ++r) acc[r] = bias;
  for (int m = 0; m < MM; ++m) {
    float wv = VW[m*256 + j];
    #pragma unroll
    for (int r = 0; r < XR; ++r) acc[r] += scw[r][m] * wv;
  }
  for (int d4 = 0; d4 < QDIM/4; ++d4) {
    float4 wq = *(const float4*)(WQT4 + d4*1024 + j*4);
    #pragma unroll
    for (int r = 0; r < XR; ++r) {
      float4 ev = *(const float4*)(&ses[r][4*d4]);
      acc[r] += ev.x*wq.x + ev.y*wq.y + ev.z*wq.z + ev.w*wq.w;
    }
  }
  int gate = j >> 6, unit = j & 63;
  #pragma unroll
  for (int r = 0; r < XR; ++r)
    if (base + r < NROWS) XW4[(size_t)(base + r)*256 + 4*unit + gate] = acc[r];
}

__global__ void k_mark(const int* __restrict__ q_data, u32* __restrict__ present){
  int i = blockIdx.x*blockDim.x + threadIdx.x;
  if (i < NSAMP) present[clampq(q_data[i])] = 1u;
}

__global__ __launch_bounds__(1024) void k_dedup(
    const u32* __restrict__ present, const u64* __restrict__ KEYT,
    u32* __restrict__ g_htab, u32* __restrict__ g_pay,
    u32* __restrict__ counter, u64* __restrict__ uniq){
  __shared__ u32 sh_tab[DHS];
  __shared__ u32 sh_pay[DHS];
  __shared__ u32 sh_cnt;
  int tid = threadIdx.x;
  for (int i = tid; i < DHS; i += 1024) sh_tab[i] = 0u;
  if (tid == 0) sh_cnt = 0u;
  __syncthreads();
  for (int n = tid; n < NROWS; n += 1024) {
    if (!present[n]) continue;
    u64 key = KEYT[n];
    u32 h = hash64(key) & DHMASK;
    while (true) {
      u32 cur = sh_tab[h];
      if (cur != 0u) {
        if (KEYT[cur-1u] == key) break;
        h = (h + 1) & DHMASK; continue;
      }
      u32 prev = atomicCAS(&sh_tab[h], 0u, (u32)(n + 1));
      if (prev == 0u) {
        u32 idx = atomicAdd(&sh_cnt, 1u);
        uniq[idx] = key;
        sh_pay[h] = idx;
        break;
      }
      if (KEYT[prev-1u] == key) break;
      h = (h + 1) & DHMASK;
    }
  }
  __syncthreads();
  for (int i = tid; i < DHS; i += 1024) {
    u32 v = sh_tab[i];
    g_htab[i] = v;
    g_pay[i]  = v ? sh_pay[i] : 0u;
  }
  if (tid == 0) *counter = sh_cnt;
}

__global__ __launch_bounds__(256) void k_rank(const u64* __restrict__ uniq,
                                              const u32* __restrict__ counter,
                                              u32* __restrict__ RANK){
  __shared__ u64 chunk[2048];
  u32 U = *counter;
  int u = blockIdx.x*256 + threadIdx.x;
  u64 mykey = (u < (int)U) ? uniq[u] : 0;
  u32 cnt = 0;
  for (u32 base = 0; base < U; base += 2048) {
    u32 n = (U - base < 2048u) ? (U - base) : 2048u;
    __syncthreads();
    for (u32 t = threadIdx.x; t < n; t += 256) chunk[t] = uniq[base + t];
    __syncthreads();
    if (u < (int)U)
      for (u32 j = 0; j < n; ++j) cnt += (chunk[j] < mykey) ? 1u : 0u;
  }
  if (u < (int)U) RANK[u] = cnt;
}

__global__ void k_qrank(const u32* __restrict__ present, const u64* __restrict__ KEYT,
                        const u32* __restrict__ g_htab, const u32* __restrict__ g_pay,
                        const u32* __restrict__ RANK, u32* __restrict__ RANKQ){
  int n = blockIdx.x*blockDim.x + threadIdx.x;
  if (n >= NROWS || !present[n]) return;
  u64 key = KEYT[n];
  u32 h = hash64(key) & DHMASK;
  while (true) {
    u32 cur = g_htab[h];
    if (cur != 0u && KEYT[cur-1u] == key) { RANKQ[n] = RANK[g_pay[h]]; return; }
    h = (h + 1) & DHMASK;
  }
}

__global__ void k_ids(const int* __restrict__ q_data, const u32* __restrict__ RANKQ,
                      float* __restrict__ out_ids){
  int i = blockIdx.x*blockDim.x + threadIdx.x;
  if (i >= NSAMP) return;
  out_ids[i] = (float)RANKQ[clampq(q_data[i])];
}

// LSTM: 4 waves per batch element, one gate per wave (64 weight floats/lane -> no
// spills). h,c replicated in all waves. XW staged per 50-step chunk into LDS ->
// zero global ops inside the step loop -> the per-step barrier drains nothing.
__global__ __launch_bounds__(256, 1) void k_lstm(
    const int* __restrict__ q_data, const float* __restrict__ XW4,
    const float* __restrict__ W_hh,
    const float* __restrict__ W_pred, const float* __restrict__ b_pred,
    const float* __restrict__ init_h, const float* __restrict__ init_c,
    float* __restrict__ out_pred){
  const int b = blockIdx.x, t = threadIdx.x;
  const int w = t >> 6, k = t & 63;           // gate, unit
  __shared__ float XWc[CH][4][HH];            // 51,200 B chunk of gate inputs
  __shared__ float A[2][4][HH];               // double-buffered pre-activations
  __shared__ float spred[CH];
  __shared__ float swp[HH];
  __shared__ int   sq[SS];
  for (int s = t; s < SS; s += 256) sq[s] = clampq(q_data[b*SS + s]);
  if (t < HH) swp[t] = W_pred[t];
  float wgt[HH];                              // W_hh row (w*64+k)
  {
    const float4* wr = (const float4*)(W_hh + (size_t)(w*HH + k)*HH);
    #pragma unroll
    for (int j4 = 0; j4 < HH/4; ++j4) {
      float4 v = wr[j4];
      wgt[4*j4+0]=v.x; wgt[4*j4+1]=v.y; wgt[4*j4+2]=v.z; wgt[4*j4+3]=v.w;
    }
  }
  float h = init_h[b*HH + k];
  float c = init_c[b*HH + k];
  float bp = b_pred[0];
  __syncthreads();

  for (int cs = 0; cs < SS; cs += CH) {
    // stage chunk: 50 rows x 256 floats, coalesced float4 gathers, scatter to [s][g][k]
    for (int rr = w; rr < CH; rr += 4) {
      float4 xv = *(const float4*)(XW4 + (size_t)sq[cs + rr]*256 + 4*k);
      XWc[rr][0][k] = xv.x; XWc[rr][1][k] = xv.y;
      XWc[rr][2][k] = xv.z; XWc[rr][3][k] = xv.w;
    }
    __syncthreads();
    for (int s = 0; s < CH; ++s) {
      float a0=0.f, a1=0.f, a2=0.f, a3=0.f;   // 4 sub-chains for ILP
      #pragma unroll
      for (int j = 0; j < 16; ++j) {
        float h0 = rl(h, j), h1 = rl(h, j+16), h2 = rl(h, j+32), h3 = rl(h, j+48);
        a0 += wgt[j]*h0; a1 += wgt[j+16]*h1; a2 += wgt[j+32]*h2; a3 += wgt[j+48]*h3;
      }
      A[s & 1][w][k] = XWc[s][w][k] + ((a0+a1)+(a2+a3));
      __syncthreads();                        // LDS-only drain (no vmem in flight)
      float ai = A[s & 1][0][k], af = A[s & 1][1][k];
      float ag = A[s & 1][2][k], ao = A[s & 1][3][k];
      c = fsigm(af)*c + fsigm(ai)*ftanh(ag);
      h = fsigm(ao)*ftanh(c);
      if (w == 0) {                           // deferred-sigmoid pred reduce
        float p = h * swp[k];
        #pragma unroll
        for (int off = 32; off > 0; off >>= 1) p += __shfl_down(p, off, 64);
        if (k == 0) spred[s] = p;
      }
    }
    __syncthreads();                          // spred visible; XWc reads done
    if (t < CH) out_pred[b*SS + cs + t] = fsigm(spred[t] + bp);
  }
}

extern "C" void kernel_launch(void* const* d_in, const int* in_sizes, int n_in,
                              void* d_out, int out_size, void* d_ws, size_t ws_size,
                              hipStream_t stream) {
  const int*   q_data  = (const int*)d_in[0];
  const float* emb     = (const float*)d_in[1];
  const float* keym    = (const float*)d_in[2];
  const float* val     = (const float*)d_in[3];
  const float* W_ih    = (const float*)d_in[4];
  const float* W_hh    = (const float*)d_in[5];
  const float* b_ih    = (const float*)d_in[6];
  const float* b_hh    = (const float*)d_in[7];
  const float* W_pred  = (const float*)d_in[8];
  const float* b_pred  = (const float*)d_in[9];
  const float* init_h  = (const float*)d_in[10];
  const float* init_c  = (const float*)d_in[11];

  char* ws = (char*)d_ws;
  float* XW4     = (float*)(ws + 0);          // 10,241,024 (CW overlaid low 32 floats/row)
  float* VW      = (float*)(ws + 10241024);   // 32,768
  u64*  KEYT     = (u64*) (ws + 10273792);    // 80,128
  u64*  uniq     = (u64*) (ws + 10353920);    // 80,128
  u32*  RANK     = (u32*) (ws + 10434048);    // 40,192
  u32*  g_htab   = (u32*) (ws + 10474240);    // 32,768
  u32*  g_pay    = (u32*) (ws + 10507008);    // 32,768
  u32*  counter  = (u32*) (ws + 10539776);    // 64
  u32*  present  = (u32*) (ws + 10539840);    // 40,064
  u32*  RANKQ    = (u32*) (ws + 10579904);    // 40,064
  float* WQT4    = (float*)(ws + 10619968);   // 524,288
  float* KT      = (float*)(ws + 11144256);   // 16,384
  float* WVT     = (float*)(ws + 11160640);   // 262,144  (ends 11,422,784)
  float* CW      = XW4;                       // overlay: CW[n*256+m]

  float* out_pred = (float*)d_out;
  float* out_ids  = out_pred + NSAMP;

  hipLaunchKernelGGL(k_tr,    dim3(784), dim3(256), 0, stream, W_ih, keym, WQT4, KT, WVT);
  hipLaunchKernelGGL(k_init,  dim3((NROWS+255)/256), dim3(256), 0, stream, present);
  hipLaunchKernelGGL(k_vw,    dim3(MM), dim3(256), 0, stream, val, WVT, VW);
  hipLaunchKernelGGL(k_attn,  dim3((NROWS+3)/4), dim3(256), 0, stream, emb, KT, CW, KEYT);
  hipLaunchKernelGGL(k_mark,  dim3((NSAMP+255)/256), dim3(256), 0, stream, q_data, present);
  hipLaunchKernelGGL(k_dedup, dim3(1), dim3(1024), 0, stream,
                     present, KEYT, g_htab, g_pay, counter, uniq);
  hipLaunchKernelGGL(k_rank,  dim3((NROWS+255)/256), dim3(256), 0, stream, uniq, counter, RANK);
  hipLaunchKernelGGL(k_qrank, dim3((NROWS+255)/256), dim3(256), 0, stream,
                     present, KEYT, g_htab, g_pay, RANK, RANKQ);
  hipLaunchKernelGGL(k_xw,    dim3((NROWS+XR-1)/XR), dim3(256), 0, stream,
                     CW, emb, VW, WQT4, b_ih, b_hh, XW4);
  hipLaunchKernelGGL(k_ids,   dim3((NSAMP+255)/256), dim3(256), 0, stream, q_data, RANKQ, out_ids);
  hipLaunchKernelGGL(k_lstm,  dim3(BB), dim3(256), 0, stream,
                     q_data, XW4, W_hh, W_pred, b_pred, init_h, init_c, out_pred);
}

// Round 13
// 276.113 us; speedup vs baseline: 4.0872x; 1.0863x over previous
//
#include <hip/hip_runtime.h>

#define BB 256
#define SS 200
#define MM 32
#define KDIM 128
#define VDIM 256
#define QDIM 128
#define HH 64
#define NROWS 10001
#define NSAMP (BB*SS)
#define INDIM (VDIM+QDIM)
#define DHS 8192
#define DHMASK (DHS-1)
#define XR 16
#define CH 50
#define NB_ATTN 2501

typedef unsigned long long u64;
typedef unsigned int u32;

__device__ __forceinline__ float fexp(float x){ return __builtin_amdgcn_exp2f(x * 1.44269504f); }
__device__ __forceinline__ float fsigm(float x){ return __builtin_amdgcn_rcpf(1.f + fexp(-x)); }
__device__ __forceinline__ float ftanh(float x){ return 1.f - 2.f*__builtin_amdgcn_rcpf(1.f + fexp(2.f*x)); }
__device__ __forceinline__ int clampq(int q){ return q < 0 ? 0 : (q > NROWS-1 ? NROWS-1 : q); }

__device__ __forceinline__ u32 hash64(u64 x){
  x ^= x >> 33; x *= 0xff51afd7ed558ccdULL;
  x ^= x >> 33; x *= 0xc4ceb9fe1a85ec53ULL;
  x ^= x >> 33;
  return (u32)x;
}

__device__ __forceinline__ u64 shflx64(u64 v, int m){
  int lo = __shfl_xor((int)(u32)v, m, 64);
  int hi = __shfl_xor((int)(u32)(v >> 32), m, 64);
  return ((u64)(u32)hi << 32) | (u32)lo;
}

// transposes + present init:
// WQT4[(d4*256+j)*4+dd]=W_ih[j][VDIM+4d4+dd]; KT[d*32+m]=key_mem[m][d];
// WVT[v*256+j]=W_ih[j][v]; present[:]=0
__global__ void k_tr(const float* __restrict__ W_ih, const float* __restrict__ key_mem,
                     float* __restrict__ WQT4, float* __restrict__ KT,
                     float* __restrict__ WVT, u32* __restrict__ present){
  int idx = blockIdx.x*256 + threadIdx.x;
  if (idx < 131072) {
    int dd = idx & 3, j = (idx >> 2) & 255, d4 = idx >> 10;
    WQT4[idx] = W_ih[j*INDIM + VDIM + 4*d4 + dd];
  } else if (idx < 135168) {
    int t = idx - 131072;
    int m = t & 31, d = t >> 5; KT[t] = key_mem[m*KDIM + d];
  } else if (idx < 200704) {
    int t = idx - 135168;
    int j = t & 255, v = t >> 8; WVT[v*256 + j] = W_ih[j*INDIM + v];
  } else {
    int t = idx - 200704;
    if (t < NROWS) present[t] = 0u;
  }
}

// fused front: blocks [0,2501) attn ; [2501,2533) vw ; [2533,2733) mark
__global__ __launch_bounds__(256) void k_front(
    const float* __restrict__ emb, const float* __restrict__ KT,
    const float* __restrict__ val, const float* __restrict__ WVT,
    const int* __restrict__ q_data,
    float* __restrict__ CW, u64* __restrict__ KEYT,
    float* __restrict__ VW, u32* __restrict__ present){
  int bid = blockIdx.x;
  if (bid < NB_ATTN) {
    // ---- attn: one wave per row ----
    int w = threadIdx.x >> 6, l = threadIdx.x & 63;
    int n = bid*4 + w;
    __shared__ float se[4][QDIM];
    bool valid = (n < NROWS);
    if (valid) {
      se[w][l]      = emb[n*QDIM + l];
      se[w][l + 64] = emb[n*QDIM + l + 64];
    }
    __syncthreads();
    int m = l & 31;
    float logit = 0.f;
    if (valid && l < 32)
      for (int d = 0; d < KDIM; ++d) logit += se[w][d] * KT[d*32 + m];
    float mx = logit;
    #pragma unroll
    for (int msk = 16; msk >= 1; msk >>= 1) mx = fmaxf(mx, __shfl_xor(mx, msk, 64));
    float e = (l < 32) ? expf(logit - mx) : 0.f;    // precise expf: trit boundaries
    float sum = e;
    #pragma unroll
    for (int msk = 16; msk >= 1; msk >>= 1) sum += __shfl_xor(sum, msk, 64);
    float cw = e / sum;
    float wv = fminf((cw - 0.075f)/0.013f, (1.0f - cw)/0.912f);
    wv = fmaxf(wv, 0.f);
    int iv = (wv >= 0.6f) ? 2 : ((wv >= 0.1f) ? 1 : 0);
    int ee = (m < 16) ? m + 16 : m - 16;   // key = kh*3^16 + kl (reference packing)
    u64 p3 = 1;
    for (int i = 0; i < 31; ++i) if (i < ee) p3 *= 3ULL;
    u64 term = (valid && l < 32) ? (u64)iv * p3 : 0ULL;
    #pragma unroll
    for (int msk = 16; msk >= 1; msk >>= 1) term += shflx64(term, msk);
    if (valid && l < 32) CW[n*256 + m] = cw;
    if (valid && l == 0) KEYT[n] = term;
  } else if (bid < NB_ATTN + MM) {
    // ---- vw: VW[m][j] = sum_v val[m][v]*WVT[v][j] ----
    int m = bid - NB_ATTN, j = threadIdx.x;
    __shared__ float sval[VDIM];
    sval[j] = val[m*VDIM + j];
    __syncthreads();
    float a0=0.f, a1=0.f, a2=0.f, a3=0.f;
    for (int v = 0; v < VDIM; v += 4) {
      a0 += sval[v+0]*WVT[(v+0)*256 + j];
      a1 += sval[v+1]*WVT[(v+1)*256 + j];
      a2 += sval[v+2]*WVT[(v+2)*256 + j];
      a3 += sval[v+3]*WVT[(v+3)*256 + j];
    }
    VW[m*256 + j] = (a0+a1)+(a2+a3);
  } else {
    // ---- mark ----
    int i = (bid - NB_ATTN - MM)*256 + threadIdx.x;
    if (i < NSAMP) present[clampq(q_data[i])] = 1u;
  }
}

// XW4 row = bias + cw.VW + emb.WqT: 16 rows/block tiled GEMM
__global__ __launch_bounds__(256) void k_xw(
    const float* __restrict__ CW, const float* __restrict__ emb,
    const float* __restrict__ VW, const float* __restrict__ WQT4,
    const float* __restrict__ b_ih, const float* __restrict__ b_hh,
    float* __restrict__ XW4){
  int base = blockIdx.x * XR;
  int j = threadIdx.x;
  __shared__ float scw[XR][32];
  __shared__ __align__(16) float ses[XR][QDIM];
  for (int idx = j; idx < XR*32; idx += 256) {
    int r = idx >> 5, m = idx & 31, n = base + r;
    scw[r][m] = (n < NROWS) ? CW[n*256 + m] : 0.f;
  }
  for (int idx = j; idx < XR*QDIM; idx += 256) {
    int r = idx >> 7, d = idx & 127, n = base + r;
    ses[r][d] = (n < NROWS) ? emb[n*QDIM + d] : 0.f;
  }
  __syncthreads();
  float bias = b_ih[j] + b_hh[j];
  float acc[XR];
  #pragma unroll
  for (int r = 0; r < XR; ++r) acc[r] = bias;
  for (int m = 0; m < MM; ++m) {
    float wv = VW[m*256 + j];
    #pragma unroll
    for (int r = 0; r < XR; ++r) acc[r] += scw[r][m] * wv;
  }
  for (int d4 = 0; d4 < QDIM/4; ++d4) {
    float4 wq = *(const float4*)(WQT4 + d4*1024 + j*4);
    #pragma unroll
    for (int r = 0; r < XR; ++r) {
      float4 ev = *(const float4*)(&ses[r][4*d4]);
      acc[r] += ev.x*wq.x + ev.y*wq.y + ev.z*wq.z + ev.w*wq.w;
    }
  }
  int gate = j >> 6, unit = j & 63;
  #pragma unroll
  for (int r = 0; r < XR; ++r)
    if (base + r < NROWS) XW4[(size_t)(base + r)*256 + 4*unit + gate] = acc[r];
}

__global__ __launch_bounds__(1024) void k_dedup(
    const u32* __restrict__ present, const u64* __restrict__ KEYT,
    u32* __restrict__ g_htab, u32* __restrict__ g_pay,
    u32* __restrict__ counter, u64* __restrict__ uniq){
  __shared__ u32 sh_tab[DHS];
  __shared__ u32 sh_pay[DHS];
  __shared__ u32 sh_cnt;
  int tid = threadIdx.x;
  for (int i = tid; i < DHS; i += 1024) sh_tab[i] = 0u;
  if (tid == 0) sh_cnt = 0u;
  __syncthreads();
  for (int n = tid; n < NROWS; n += 1024) {
    if (present[n] != 1u) continue;
    u64 key = KEYT[n];
    u32 h = hash64(key) & DHMASK;
    while (true) {
      u32 cur = sh_tab[h];
      if (cur != 0u) {
        if (KEYT[cur-1u] == key) break;
        h = (h + 1) & DHMASK; continue;
      }
      u32 prev = atomicCAS(&sh_tab[h], 0u, (u32)(n + 1));
      if (prev == 0u) {
        u32 idx = atomicAdd(&sh_cnt, 1u);
        uniq[idx] = key;
        sh_pay[h] = idx;
        break;
      }
      if (KEYT[prev-1u] == key) break;
      h = (h + 1) & DHMASK;
    }
  }
  __syncthreads();
  for (int i = tid; i < DHS; i += 1024) {
    u32 v = sh_tab[i];
    g_htab[i] = v;
    g_pay[i]  = v ? sh_pay[i] : 0u;
  }
  if (tid == 0) *counter = sh_cnt;
}

__global__ __launch_bounds__(256) void k_rank(const u64* __restrict__ uniq,
                                              const u32* __restrict__ counter,
                                              u32* __restrict__ RANK){
  __shared__ u64 chunk[2048];
  u32 U = *counter;
  int u = blockIdx.x*256 + threadIdx.x;
  u64 mykey = (u < (int)U) ? uniq[u] : 0;
  u32 cnt = 0;
  for (u32 base = 0; base < U; base += 2048) {
    u32 n = (U - base < 2048u) ? (U - base) : 2048u;
    __syncthreads();
    for (u32 t = threadIdx.x; t < n; t += 256) chunk[t] = uniq[base + t];
    __syncthreads();
    if (u < (int)U)
      for (u32 j = 0; j < n; ++j) cnt += (chunk[j] < mykey) ? 1u : 0u;
  }
  if (u < (int)U) RANK[u] = cnt;
}

__global__ void k_qrank(const u32* __restrict__ present, const u64* __restrict__ KEYT,
                        const u32* __restrict__ g_htab, const u32* __restrict__ g_pay,
                        const u32* __restrict__ RANK, u32* __restrict__ RANKQ){
  int n = blockIdx.x*blockDim.x + threadIdx.x;
  if (n >= NROWS || present[n] != 1u) return;
  u64 key = KEYT[n];
  u32 h = hash64(key) & DHMASK;
  while (true) {
    u32 cur = g_htab[h];
    if (cur != 0u && KEYT[cur-1u] == key) { RANKQ[n] = RANK[g_pay[h]]; return; }
    h = (h + 1) & DHMASK;
  }
}

__global__ void k_ids(const int* __restrict__ q_data, const u32* __restrict__ RANKQ,
                      float* __restrict__ out_ids){
  int i = blockIdx.x*blockDim.x + threadIdx.x;
  if (i >= NSAMP) return;
  out_ids[i] = (float)RANKQ[clampq(q_data[i])];
}

// LSTM v3: wave w owns units 16w..16w+15; lane = (gate g = l>>4, u = l&15).
// Every lane holds full h (64 VGPRs) -> dot is 64 pure FMAs, no readlane.
// Gate exchange intra-wave via 3 shfl_xor. Per step: ONE barrier + one LDS RT
// (h broadcast via Hbuf, which doubles as h-history for the deferred pred).
__global__ __launch_bounds__(256, 1) void k_lstm(
    const int* __restrict__ q_data, const float* __restrict__ XW4,
    const float* __restrict__ W_hh,
    const float* __restrict__ W_pred, const float* __restrict__ b_pred,
    const float* __restrict__ init_h, const float* __restrict__ init_c,
    float* __restrict__ out_pred){
  const int b = blockIdx.x, t = threadIdx.x;
  const int w = t >> 6, l = t & 63;
  const int g = l >> 4, u = l & 15;
  const int unit = w*16 + u;
  __shared__ float XWc[CH][256];        // [s][w*64 + g*16 + u]  51,200 B
  __shared__ __align__(16) float Hbuf[SS][68];  // h history; stride 68: b128-aligned, 2-way banks
  __shared__ float swp[HH];
  __shared__ int   sq[SS];
  for (int s = t; s < SS; s += 256) sq[s] = clampq(q_data[b*SS + s]);
  if (t < HH) swp[t] = W_pred[t];

  float wgt[HH];                        // W_hh row (g*64 + unit)
  {
    const float4* wr = (const float4*)(W_hh + (size_t)(g*HH + unit)*HH);
    #pragma unroll
    for (int j4 = 0; j4 < HH/4; ++j4) {
      float4 v = wr[j4];
      wgt[4*j4+0]=v.x; wgt[4*j4+1]=v.y; wgt[4*j4+2]=v.z; wgt[4*j4+3]=v.w;
    }
  }
  float hfull[HH];                      // replicated h (identical in all lanes)
  {
    const float4* ih = (const float4*)(init_h + b*HH);
    #pragma unroll
    for (int j4 = 0; j4 < HH/4; ++j4) {
      float4 v = ih[j4];
      hfull[4*j4+0]=v.x; hfull[4*j4+1]=v.y; hfull[4*j4+2]=v.z; hfull[4*j4+3]=v.w;
    }
  }
  float c  = init_c[b*HH + unit];
  float bp = b_pred[0];
  __syncthreads();

  for (int cs = 0; cs < SS; cs += CH) {
    // stage chunk: coalesced float4 per unit row, scatter to gate-major slots
    for (int rr = w; rr < CH; rr += 4) {
      float4 xv = *(const float4*)(XW4 + (size_t)sq[cs + rr]*256 + 4*l);
      int wp = l >> 4, up = l & 15;
      XWc[rr][wp*64 +  0 + up] = xv.x;
      XWc[rr][wp*64 + 16 + up] = xv.y;
      XWc[rr][wp*64 + 32 + up] = xv.z;
      XWc[rr][wp*64 + 48 + up] = xv.w;
    }
    __syncthreads();
    for (int sl = 0; sl < CH; ++sl) {
      const int s = cs + sl;
      float a0=0.f, a1=0.f, a2=0.f, a3=0.f;
      #pragma unroll
      for (int j = 0; j < 16; ++j) {
        a0 += wgt[j   ]*hfull[j   ];
        a1 += wgt[j+16]*hfull[j+16];
        a2 += wgt[j+32]*hfull[j+32];
        a3 += wgt[j+48]*hfull[j+48];
      }
      float a = XWc[sl][w*64 + l] + ((a0+a1)+(a2+a3));
      // gather the 4 gate values for this unit (v[m] = gate g^m)
      float v0 = a;
      float v1 = __shfl_xor(a, 16, 64);
      float v2 = __shfl_xor(a, 32, 64);
      float v3 = __shfl_xor(v1, 32, 64);
      float vv[4] = {v0, v1, v2, v3};
      float ii = vv[g], ff = vv[g^1], gg = vv[g^2], oo = vv[g^3];
      c = fsigm(ff)*c + fsigm(ii)*ftanh(gg);
      float hh = fsigm(oo)*ftanh(c);
      if (g == 0) Hbuf[s][unit] = hh;
      __syncthreads();
      const float4* hb = (const float4*)(&Hbuf[s][0]);  // uniform-address broadcast
      #pragma unroll
      for (int j4 = 0; j4 < HH/4; ++j4) {
        float4 v = hb[j4];
        hfull[4*j4+0]=v.x; hfull[4*j4+1]=v.y; hfull[4*j4+2]=v.z; hfull[4*j4+3]=v.w;
      }
    }
  }
  // deferred pred epilogue (Hbuf already sync'd by last step's barrier + reads)
  __syncthreads();
  if (t < SS) {
    float acc = 0.f;
    #pragma unroll 16
    for (int kk = 0; kk < HH; ++kk) {
      int k2 = (kk + t) & 63;          // swizzle: conflict-free banks
      acc += Hbuf[t][k2] * swp[k2];
    }
    out_pred[b*SS + t] = fsigm(acc + bp);
  }
}

extern "C" void kernel_launch(void* const* d_in, const int* in_sizes, int n_in,
                              void* d_out, int out_size, void* d_ws, size_t ws_size,
                              hipStream_t stream) {
  const int*   q_data  = (const int*)d_in[0];
  const float* emb     = (const float*)d_in[1];
  const float* keym    = (const float*)d_in[2];
  const float* val     = (const float*)d_in[3];
  const float* W_ih    = (const float*)d_in[4];
  const float* W_hh    = (const float*)d_in[5];
  const float* b_ih    = (const float*)d_in[6];
  const float* b_hh    = (const float*)d_in[7];
  const float* W_pred  = (const float*)d_in[8];
  const float* b_pred  = (const float*)d_in[9];
  const float* init_h  = (const float*)d_in[10];
  const float* init_c  = (const float*)d_in[11];

  char* ws = (char*)d_ws;
  float* XW4     = (float*)(ws + 0);          // 10,241,024 (CW overlaid low 32 floats/row)
  float* VW      = (float*)(ws + 10241024);   // 32,768
  u64*  KEYT     = (u64*) (ws + 10273792);    // 80,128
  u64*  uniq     = (u64*) (ws + 10353920);    // 80,128
  u32*  RANK     = (u32*) (ws + 10434048);    // 40,192
  u32*  g_htab   = (u32*) (ws + 10474240);    // 32,768
  u32*  g_pay    = (u32*) (ws + 10507008);    // 32,768
  u32*  counter  = (u32*) (ws + 10539776);    // 64
  u32*  present  = (u32*) (ws + 10539840);    // 40,064
  u32*  RANKQ    = (u32*) (ws + 10579904);    // 40,064
  float* WQT4    = (float*)(ws + 10619968);   // 524,288
  float* KT      = (float*)(ws + 11144256);   // 16,384
  float* WVT     = (float*)(ws + 11160640);   // 262,144
  float* CW      = XW4;                       // overlay: CW[n*256+m]

  float* out_pred = (float*)d_out;
  float* out_ids  = out_pred + NSAMP;

  hipLaunchKernelGGL(k_tr,    dim3(824), dim3(256), 0, stream,
                     W_ih, keym, WQT4, KT, WVT, present);
  hipLaunchKernelGGL(k_front, dim3(NB_ATTN + MM + 200), dim3(256), 0, stream,
                     emb, KT, val, WVT, q_data, CW, KEYT, VW, present);
  hipLaunchKernelGGL(k_dedup, dim3(1), dim3(1024), 0, stream,
                     present, KEYT, g_htab, g_pay, counter, uniq);
  hipLaunchKernelGGL(k_rank,  dim3((NROWS+255)/256), dim3(256), 0, stream, uniq, counter, RANK);
  hipLaunchKernelGGL(k_qrank, dim3((NROWS+255)/256), dim3(256), 0, stream,
                     present, KEYT, g_htab, g_pay, RANK, RANKQ);
  hipLaunchKernelGGL(k_xw,    dim3((NROWS+XR-1)/XR), dim3(256), 0, stream,
                     CW, emb, VW, WQT4, b_ih, b_hh, XW4);
  hipLaunchKernelGGL(k_ids,   dim3((NSAMP+255)/256), dim3(256), 0, stream, q_data, RANKQ, out_ids);
  hipLaunchKernelGGL(k_lstm,  dim3(BB), dim3(256), 0, stream,
                     q_data, XW4, W_hh, W_pred, b_pred, init_h, init_c, out_pred);
}